// Round 9
// baseline (318.499 us; speedup 1.0000x reference)
//
#include <hip/hip_runtime.h>
#include <hip/hip_bf16.h>
#include <hip/hip_fp8.h>

typedef __attribute__((ext_vector_type(8))) short short8;
typedef __attribute__((ext_vector_type(4))) short short4_t;
typedef __attribute__((ext_vector_type(4))) float floatx4;
typedef __attribute__((ext_vector_type(2))) float floatx2;

constexpr int NB  = 256;    // dst buckets
constexpr int CAP = 6144;   // pairs per bucket (mean 4096 for uniform graph)

__device__ __forceinline__ unsigned short f2bf(float f){
  unsigned int u = __float_as_uint(f);
  u += 0x7FFF + ((u >> 16) & 1);           // RNE
  return (unsigned short)(u >> 16);
}
__device__ __forceinline__ float bf2f(unsigned short h){
  return __uint_as_float(((unsigned int)h) << 16);
}
__device__ __forceinline__ float lrelu(float x){ return x > 0.f ? x : 0.2f * x; }
__device__ __forceinline__ float eluf(float x){ return x > 0.f ? x : (__expf(x) - 1.f); }

__device__ __forceinline__ unsigned char f2fp8(float f){
  __hip_fp8_e4m3 t(f);
  return (unsigned char)t.__x;
}
__device__ __forceinline__ float fp82f(unsigned char b){
  __hip_fp8_e4m3 t;
  t.__x = (__hip_fp8_storage_t)b;
  return (float)t;
}

template<bool HI>
__device__ __forceinline__ floatx2 fp8pk2(unsigned int v){
#if defined(__has_builtin) && __has_builtin(__builtin_amdgcn_cvt_pk_f32_fp8)
  return __builtin_amdgcn_cvt_pk_f32_fp8((int)v, HI);
#else
  floatx2 r;
  constexpr int sh = HI ? 16 : 0;
  r.x = fp82f((unsigned char)((v >> sh) & 0xFF));
  r.y = fp82f((unsigned char)((v >> (sh + 8)) & 0xFF));
  return r;
#endif
}

// HW packed fp8 encode of 4 floats -> 4 bytes (returned in uint, b0..b3)
__device__ __forceinline__ unsigned int f32x4_to_fp8(float a0, float a1, float a2, float a3){
#if defined(__has_builtin) && __has_builtin(__builtin_amdgcn_cvt_pk_fp8_f32)
  int w = 0;
  w = __builtin_amdgcn_cvt_pk_fp8_f32(a0, a1, w, false);   // bytes 0,1
  w = __builtin_amdgcn_cvt_pk_fp8_f32(a2, a3, w, true);    // bytes 2,3
  return (unsigned int)w;
#else
  return (unsigned int)f2fp8(a0) | ((unsigned int)f2fp8(a1) << 8) |
         ((unsigned int)f2fp8(a2) << 16) | ((unsigned int)f2fp8(a3) << 24);
#endif
}

// chunk-stratified scramble of sorted rank p in [0,512):
// 64 consecutive ranks (one agg4g block) stay together -> degree-uniform
// blocks (cheap intra-block barrier); chunk order rotated -> grid balance.
__device__ __forceinline__ int scr512(int p){
  int c = p >> 6, s = p & 63;              // 8 chunks of 64
  int cc = ((c & 3) << 1) | (c >> 2);      // rotate-left-1 of 3-bit chunk id
  return (cc << 6) | s;
}

// async global->LDS, 16B per lane; LDS dest = base + lane*16
__device__ __forceinline__ void gload16(const unsigned short* g, unsigned short* l){
  __builtin_amdgcn_global_load_lds(
      (const __attribute__((address_space(1))) unsigned int*)(const void*)g,
      (__attribute__((address_space(3))) unsigned int*)(void*)l,
      16, 0, 0);
}

// ---------------- fused: edge bucket-partition + weight prep (independent work) ----------------
// bbuf word packing: src (17b) | ldst (9b, <<17) | x[src] (3b, <<26)
__global__ __launch_bounds__(256) void part_prep_k(const int* __restrict__ ei, int E, int shift,
                                                   const int* __restrict__ x,
                                                   int* __restrict__ gcnt,
                                                   unsigned* __restrict__ bbuf, int PB,
                                                   const float* __restrict__ W2,
                                                   unsigned short* __restrict__ Wp2,
                                                   const float* __restrict__ W3,
                                                   unsigned short* __restrict__ Wp3,
                                                   const float* __restrict__ emb,
                                                   const float* __restrict__ W1,
                                                   const float* __restrict__ a1s,
                                                   const float* __restrict__ a1d,
                                                   const float* __restrict__ a3s,
                                                   const float* __restrict__ a3d,
                                                   float* __restrict__ T1,
                                                   float* __restrict__ wt_tab,
                                                   float* __restrict__ w3s,
                                                   float* __restrict__ w3d){
  int blk = blockIdx.x;
  int tid = threadIdx.x;
  if (blk < PB){
    __shared__ int hist[NB];
    __shared__ int base[NB];
    hist[tid] = 0;
    __syncthreads();
    int blk_start = blk * 4096;
    int ldmask = (1 << shift) - 1;
    unsigned word[16];
    int bkt[16], lp[16];
    #pragma unroll
    for (int k = 0; k < 16; k++){
      int i = blk_start + k * 256 + tid;
      if (i < E){
        int dst = ei[E + i];
        int s = ei[i];
        int xs = x[s];                       // 512KB table, L2-resident
        bkt[k] = dst >> shift;
        word[k] = (unsigned)s | ((unsigned)(dst & ldmask) << 17) | ((unsigned)xs << 26);
        lp[k] = atomicAdd(&hist[bkt[k]], 1);
      } else {
        bkt[k] = -1;
      }
    }
    __syncthreads();
    base[tid] = atomicAdd(&gcnt[tid], hist[tid]);
    __syncthreads();
    #pragma unroll
    for (int k = 0; k < 16; k++){
      if (bkt[k] >= 0){
        int b = bkt[k];
        bbuf[(size_t)b * CAP + base[b] + lp[k]] = word[k];
      }
    }
    return;
  }
  int b = blk - PB;
  if (b < 256){                      // W2 [256,256] -> Wp2[n*256+k]
    int idx = b * 256 + tid;
    int k = idx >> 8, nn = idx & 255;
    Wp2[nn * 256 + k] = f2bf(W2[idx]);
  } else if (b < 320){               // W3 [256,64] -> Wp3[n*256+k]
    int idx = (b - 256) * 256 + tid;
    int k = idx >> 6, nn = idx & 63;
    Wp3[nn * 256 + k] = f2bf(W3[idx]);
  } else {                           // conv1 tables + conv3 alpha vectors
    __shared__ float t_lds[1280];
    __shared__ float as_l[20], ad_l[20];
    // w3s/w3d: W3 (256x64) @ a3s/a3d -> 256-vecs (fused conv3 alpha path)
    {
      float ss = 0.f, sd = 0.f;
      for (int n = 0; n < 64; n++){
        float wv = W3[tid * 64 + n];
        ss += wv * a3s[n];
        sd += wv * a3d[n];
      }
      w3s[tid] = ss;
      w3d[tid] = sd;
    }
    for (int i = tid; i < 1280; i += 256){
      int r = i >> 8, c = i & 255;
      float s = 0.f;
      for (int k = 0; k < 64; k++) s += emb[r * 64 + k] * W1[k * 256 + c];
      t_lds[i] = s;
      T1[i] = s;
    }
    __syncthreads();
    if (tid < 20){
      int r = tid >> 2, hh = tid & 3;
      float ss = 0.f, sd = 0.f;
      for (int c = 0; c < 64; c++){
        float f = t_lds[r * 256 + hh * 64 + c];
        ss += f * a1s[hh * 64 + c];
        sd += f * a1d[hh * 64 + c];
      }
      as_l[tid] = ss;
      ad_l[tid] = sd;
    }
    __syncthreads();
    if (tid < 100){
      int xd = tid / 20, rest = tid % 20;      // rest = xs*4+h
      int h = rest & 3;
      wt_tab[tid] = __expf(lrelu(as_l[rest] + ad_l[xd * 4 + h]));
    }
  }
}

__global__ __launch_bounds__(256) void bscan_k(const int* __restrict__ gcnt,
                                               int* __restrict__ gbase,
                                               int* __restrict__ row_ptr, int N, int dpb){
  __shared__ int s[NB];
  int t = threadIdx.x;
  int v = gcnt[t] + dpb;
  s[t] = v;
  __syncthreads();
  #pragma unroll
  for (int off = 1; off < NB; off <<= 1){
    int u = (t >= off) ? s[t - off] : 0;
    __syncthreads();
    s[t] += u;
    __syncthreads();
  }
  gbase[t] = s[t] - v;
  if (t == NB - 1){ gbase[NB] = s[t]; row_ptr[N] = s[t]; }
}

// sort packed words into CSR; emit degree-sorted chunk-stratified perm AND the
// per-dst 5-bin x-value histogram (cnt5, packed u8x5 in a uint2) for conv1.
__global__ __launch_bounds__(256) void sort_k(const unsigned* __restrict__ bbuf,
                                              const int* __restrict__ gcnt,
                                              const int* __restrict__ gbase,
                                              const int* __restrict__ x,
                                              int* __restrict__ row_ptr,
                                              int* __restrict__ sorted_src,
                                              int* __restrict__ perm,
                                              uint2* __restrict__ cnt5, int dpb){
  __shared__ int counts[512];
  __shared__ int curs[512];
  __shared__ int wsum[256];
  __shared__ int sortedL[CAP + 512];
  __shared__ int dh[64];
  __shared__ int h5[512 * 5];
  int b = blockIdx.x, tid = threadIdx.x;
  int cnt = gcnt[b];
  int dstBase = b * dpb;
  int gb = gbase[b];
  counts[tid] = 0;
  counts[tid + 256] = 0;
  for (int i = tid; i < dpb * 5; i += 256) h5[i] = 0;
  __syncthreads();
  for (int i = tid; i < cnt; i += 256){
    unsigned pw = bbuf[(size_t)b * CAP + i];
    atomicAdd(&counts[(pw >> 17) & (dpb - 1)], 1);
  }
  // self-loop x-values (each dst's own x counts once)
  {
    int x0 = x[dstBase + 2 * tid];
    int x1 = x[dstBase + 2 * tid + 1];
    atomicAdd(&h5[(2 * tid) * 5 + x0], 1);
    atomicAdd(&h5[(2 * tid + 1) * 5 + x1], 1);
  }
  __syncthreads();
  int c0 = counts[2 * tid] + 1;
  int c1 = counts[2 * tid + 1] + 1;
  int sum = c0 + c1;
  wsum[tid] = sum;
  __syncthreads();
  #pragma unroll
  for (int off = 1; off < 256; off <<= 1){
    int u = (tid >= off) ? wsum[tid - off] : 0;
    __syncthreads();
    wsum[tid] += u;
    __syncthreads();
  }
  int ex = wsum[tid] - sum;
  int ro0 = ex, ro1 = ex + c0;
  curs[2 * tid] = ro0 + 1;          // slot ro reserved for self-loop
  curs[2 * tid + 1] = ro1 + 1;
  sortedL[ro0] = dstBase + 2 * tid;
  sortedL[ro1] = dstBase + 2 * tid + 1;
  row_ptr[dstBase + 2 * tid] = gb + ro0;
  row_ptr[dstBase + 2 * tid + 1] = gb + ro1;
  __syncthreads();
  for (int i = tid; i < cnt; i += 256){
    unsigned pw = bbuf[(size_t)b * CAP + i];
    int ldst = (pw >> 17) & (dpb - 1);
    int pos = atomicAdd(&curs[ldst], 1);
    sortedL[pos] = (int)(pw & 0x1FFFF);
    atomicAdd(&h5[ldst * 5 + (pw >> 26)], 1);
  }
  __syncthreads();
  int tot = cnt + dpb;
  for (int i = tid; i < tot; i += 256) sorted_src[gb + i] = sortedL[i];

  // pack per-dst 5-bin counts: bytes v0..v3 in .x, v4 in .y
  {
    int d0 = 2 * tid, d1 = 2 * tid + 1;
    unsigned lo0 = (unsigned)h5[d0 * 5 + 0] | ((unsigned)h5[d0 * 5 + 1] << 8) |
                   ((unsigned)h5[d0 * 5 + 2] << 16) | ((unsigned)h5[d0 * 5 + 3] << 24);
    unsigned lo1 = (unsigned)h5[d1 * 5 + 0] | ((unsigned)h5[d1 * 5 + 1] << 8) |
                   ((unsigned)h5[d1 * 5 + 2] << 16) | ((unsigned)h5[d1 * 5 + 3] << 24);
    cnt5[dstBase + d0] = make_uint2(lo0, (unsigned)h5[d0 * 5 + 4]);
    cnt5[dstBase + d1] = make_uint2(lo1, (unsigned)h5[d1 * 5 + 4]);
  }

  // ---- degree-sorted permutation (counting sort, 64 bins), chunk-stratified ----
  __syncthreads();
  if (tid < 64) dh[tid] = 0;
  __syncthreads();
  int dg0 = c0 < 63 ? c0 : 63;
  int dg1 = c1 < 63 ? c1 : 63;
  int r0 = atomicAdd(&dh[dg0], 1);
  int r1 = atomicAdd(&dh[dg1], 1);
  __syncthreads();
  if (tid == 0){
    int run = 0;
    for (int i = 0; i < 64; i++){ int c = dh[i]; dh[i] = run; run += c; }
  }
  __syncthreads();
  perm[dstBase + scr512(dh[dg0] + r0)] = dstBase + 2 * tid;
  perm[dstBase + scr512(dh[dg1] + r1)] = dstBase + 2 * tid + 1;
}

// ---------------- LDS-staged MFMA GEMM, fused alpha epilogues ----------------
template<int BN, int MODE, bool F8OUT>
__global__ __launch_bounds__(256) void gemm_lds_k(const unsigned short* __restrict__ A,
                                                  const unsigned short* __restrict__ Wp,
                                                  void* __restrict__ Cout, int Nc,
                                                  const float* __restrict__ a_src,
                                                  const float* __restrict__ a_dst,
                                                  float* __restrict__ as_arr,
                                                  float* __restrict__ ad_arr){
  constexpr int K = 256;
  constexpr int NT = BN / 32;               // col tiles per wave (4 or 2)
  __shared__ unsigned short Alds[128 * 32];
  __shared__ unsigned short Blds[BN * 32];
  __shared__ float asl[128], adl[128];
  __shared__ float pas[128][2], pad[128][2];
  int tid = threadIdx.x;
  int w = tid >> 6, l = tid & 63;
  int r16 = l & 15, quad = l >> 4;
  int wr = w >> 1, wc = w & 1;
  int mBase = blockIdx.x * 128;
  int nBase = blockIdx.y * BN;

  if constexpr (MODE == 1){
    if (tid < 128){ asl[tid] = a_src[nBase + tid]; adl[tid] = a_dst[nBase + tid]; }
  }
  if constexpr (MODE == 2){
    if (tid < 64){ asl[tid] = a_src[tid]; adl[tid] = a_dst[tid]; }
  }

  int arow = l >> 2;
  int kcol = (l & 3) * 8;                   // shorts
  const unsigned short* gA0 = A + (size_t)(mBase + w * 32 + arow) * K + kcol;
  const unsigned short* gA1 = gA0 + (size_t)16 * K;
  unsigned short* lA0 = &Alds[(w * 32) * 32];
  unsigned short* lA1 = &Alds[(w * 32 + 16) * 32];
  const unsigned short* gB0;
  const unsigned short* gB1 = nullptr;
  unsigned short* lB0;
  unsigned short* lB1 = nullptr;
  if constexpr (BN == 128){
    gB0 = Wp + (size_t)(nBase + w * 32 + arow) * K + kcol;
    gB1 = gB0 + (size_t)16 * K;
    lB0 = &Blds[(w * 32) * 32];
    lB1 = &Blds[(w * 32 + 16) * 32];
  } else {
    gB0 = Wp + (size_t)(nBase + w * 16 + arow) * K + kcol;
    lB0 = &Blds[(w * 16) * 32];
  }

  floatx4 acc[4][NT];
  #pragma unroll
  for (int mt = 0; mt < 4; mt++)
    #pragma unroll
    for (int nt = 0; nt < NT; nt++){ floatx4 z = {0.f,0.f,0.f,0.f}; acc[mt][nt] = z; }

  for (int kt = 0; kt < 8; kt++){
    int ko = kt * 32;
    gload16(gA0 + ko, lA0);
    gload16(gA1 + ko, lA1);
    gload16(gB0 + ko, lB0);
    if constexpr (BN == 128) gload16(gB1 + ko, lB1);
    __syncthreads();
    short8 af[4], bfr[NT];
    #pragma unroll
    for (int mt = 0; mt < 4; mt++)
      af[mt] = *(const short8*)&Alds[(wr * 64 + mt * 16 + r16) * 32 + quad * 8];
    #pragma unroll
    for (int nt = 0; nt < NT; nt++)
      bfr[nt] = *(const short8*)&Blds[(wc * (BN / 2) + nt * 16 + r16) * 32 + quad * 8];
    #pragma unroll
    for (int mt = 0; mt < 4; mt++)
      #pragma unroll
      for (int nt = 0; nt < NT; nt++)
        acc[mt][nt] = __builtin_amdgcn_mfma_f32_16x16x32_bf16(af[mt], bfr[nt], acc[mt][nt], 0, 0, 0);
    __syncthreads();
  }

  // epilogue: C/D layout col=lane&15, row=quad*4+reg
  #pragma unroll
  for (int mt = 0; mt < 4; mt++){
    #pragma unroll
    for (int nt = 0; nt < NT; nt++){
      if constexpr (F8OUT){
        unsigned int pk = f32x4_to_fp8(acc[mt][nt][0] * 64.f, acc[mt][nt][1] * 64.f,
                                       acc[mt][nt][2] * 64.f, acc[mt][nt][3] * 64.f);
        int col = nBase + wc * (BN / 2) + nt * 16 + r16;
        int row0 = mBase + wr * 64 + mt * 16 + quad * 4;
        #pragma unroll
        for (int r = 0; r < 4; r++)
          ((unsigned char*)Cout)[(size_t)(row0 + r) * Nc + col] =
              (unsigned char)((pk >> (r * 8)) & 0xFF);
      } else {
        #pragma unroll
        for (int r = 0; r < 4; r++){
          int row = mBase + wr * 64 + mt * 16 + quad * 4 + r;
          int col = nBase + wc * (BN / 2) + nt * 16 + r16;
          ((unsigned short*)Cout)[(size_t)row * Nc + col] = f2bf(acc[mt][nt][r]);
        }
      }
    }
  }
  if constexpr (MODE == 1){
    int head = (nBase + wc * 64) >> 6;
    #pragma unroll
    for (int mt = 0; mt < 4; mt++){
      #pragma unroll
      for (int r = 0; r < 4; r++){
        float ps = 0.f, pd = 0.f;
        #pragma unroll
        for (int nt = 0; nt < NT; nt++){
          float v = acc[mt][nt][r];
          int ci = wc * 64 + nt * 16 + r16;
          ps += v * asl[ci];
          pd += v * adl[ci];
        }
        ps += __shfl_xor(ps, 1, 64); ps += __shfl_xor(ps, 2, 64);
        ps += __shfl_xor(ps, 4, 64); ps += __shfl_xor(ps, 8, 64);
        pd += __shfl_xor(pd, 1, 64); pd += __shfl_xor(pd, 2, 64);
        pd += __shfl_xor(pd, 4, 64); pd += __shfl_xor(pd, 8, 64);
        if (r16 == 0){
          int row = mBase + wr * 64 + mt * 16 + quad * 4 + r;
          as_arr[row * 4 + head] = ps;
          ad_arr[row * 4 + head] = pd;
        }
      }
    }
  }
  if constexpr (MODE == 2){
    #pragma unroll
    for (int mt = 0; mt < 4; mt++){
      #pragma unroll
      for (int r = 0; r < 4; r++){
        float ps = 0.f, pd = 0.f;
        #pragma unroll
        for (int nt = 0; nt < NT; nt++){
          float v = acc[mt][nt][r];
          int ci = wc * 32 + nt * 16 + r16;
          ps += v * asl[ci];
          pd += v * adl[ci];
        }
        ps += __shfl_xor(ps, 1, 64); ps += __shfl_xor(ps, 2, 64);
        ps += __shfl_xor(ps, 4, 64); ps += __shfl_xor(ps, 8, 64);
        pd += __shfl_xor(pd, 1, 64); pd += __shfl_xor(pd, 2, 64);
        pd += __shfl_xor(pd, 4, 64); pd += __shfl_xor(pd, 8, 64);
        if (r16 == 0){
          int lr = wr * 64 + mt * 16 + quad * 4 + r;
          pas[lr][wc] = ps;
          pad[lr][wc] = pd;
        }
      }
    }
    __syncthreads();
    if (tid < 128){
      as_arr[mBase + tid] = pas[tid][0] + pas[tid][1];
      ad_arr[mBase + tid] = pad[tid][0] + pad[tid][1];
    }
  }
}

// ---------------- conv1 aggregation: counts precomputed in sort_k ----------------

__global__ __launch_bounds__(256) void agg1_k(const int* __restrict__ x,
                                              const float* __restrict__ T1,
                                              const float* __restrict__ wt_tab,
                                              const uint2* __restrict__ cnt5,
                                              const float* __restrict__ bias,
                                              unsigned short* __restrict__ outb){
  __shared__ float t_lds[1280];
  __shared__ float wt_l[100], b_lds[256];
  __shared__ float cnt_lds[256][5];
  __shared__ int xd_lds[256];
  int tid = threadIdx.x;
  for (int i = tid; i < 1280; i += 256) t_lds[i] = T1[i];
  if (tid < 100) wt_l[tid] = wt_tab[tid];
  b_lds[tid] = bias[tid];
  int d = blockIdx.x * 256 + tid;
  uint2 cw = cnt5[d];
  xd_lds[tid] = x[d];
  cnt_lds[tid][0] = (float)(cw.x & 0xFF);
  cnt_lds[tid][1] = (float)((cw.x >> 8) & 0xFF);
  cnt_lds[tid][2] = (float)((cw.x >> 16) & 0xFF);
  cnt_lds[tid][3] = (float)(cw.x >> 24);
  cnt_lds[tid][4] = (float)(cw.y & 0xFF);
  __syncthreads();
  // wave per dst, lane covers 4 channels
  int w = tid >> 6, l = tid & 63;
  int head = l >> 4;
  int c0i = l * 4;
  for (int dl = w; dl < 256; dl += 4){
    int dd = blockIdx.x * 256 + dl;
    int xd20 = xd_lds[dl] * 20;
    float ws[5];
    float den = 0.f;
    #pragma unroll
    for (int v2 = 0; v2 < 5; v2++){
      float wv = wt_l[xd20 + v2 * 4 + head] * cnt_lds[dl][v2];
      ws[v2] = wv;
      den += wv;
    }
    float inv = 1.f / (den + 1e-16f);
    float num[4] = {0.f, 0.f, 0.f, 0.f};
    #pragma unroll
    for (int v2 = 0; v2 < 5; v2++){
      const float4 row = *(const float4*)&t_lds[v2 * 256 + c0i];
      num[0] += ws[v2] * row.x;
      num[1] += ws[v2] * row.y;
      num[2] += ws[v2] * row.z;
      num[3] += ws[v2] * row.w;
    }
    short4_t ov;
    #pragma unroll
    for (int j = 0; j < 4; j++)
      ov[j] = (short)f2bf(eluf(num[j] * inv + b_lds[c0i + j]));
    *(short4_t*)(outb + (size_t)dd * 256 + c0i) = ov;
  }
}

// ---------------- conv2 aggregation + FUSED conv3 GEMM (64 dsts/block) ----------------
// Quarter-wave per dst, 4 dsts sequentially per quarter-wave. Conv3 alphas are
// computed in the GATHER epilogue via precomputed w3s=W3@a3s, w3d=W3@a3d
// (as3[d] = h2out[d]·w3s), killing the MFMA-phase shuffle machinery. MFMA phase
// is just 8 reg B-frags + 32 MFMA + direct coalesced fp8 byte-stores to h3out
// (no h3st LDS -> no bank conflicts, one less barrier).

__global__ __launch_bounds__(256) void agg4g_k(const unsigned char* __restrict__ h8,
                                               const float* __restrict__ as_arr,
                                               const float* __restrict__ ad_arr,
                                               const int* __restrict__ row_ptr,
                                               const int* __restrict__ sorted_src,
                                               const int* __restrict__ perm,
                                               const float* __restrict__ bias,
                                               const unsigned short* __restrict__ Wp3,
                                               const float* __restrict__ w3s,
                                               const float* __restrict__ w3d,
                                               unsigned char* __restrict__ h3out,
                                               float* __restrict__ as3,
                                               float* __restrict__ ad3){
  constexpr int LDK = 264;                  // 256 + 8 pad (bank-spread)
  __shared__ unsigned short hlds[64 * LDK]; // 33.8 KB
  __shared__ float w3sl[272], w3dl[272];    // 17-padded slices (conflict-free)
  __shared__ int dlds[64];
  int tid = threadIdx.x;
  {
    int qq = tid >> 4, jj = tid & 15;
    w3sl[qq * 17 + jj] = w3s[tid];
    w3dl[qq * 17 + jj] = w3d[tid];
  }
  int w = tid >> 6, l = tid & 63;
  int g = l >> 4, q = l & 15;               // group (dst), lane-in-group
  int rr = w * 4 + g;                       // row within 16-row group
  unsigned coff = (unsigned)(q * 16);       // byte offset in fp8 row
  int head = q >> 2;
  int cb = q * 16;
  float4 bv0 = *(const float4*)&bias[cb];
  float4 bv1 = *(const float4*)&bias[cb + 4];
  float4 bv2 = *(const float4*)&bias[cb + 8];
  float4 bv3 = *(const float4*)&bias[cb + 12];
  float bb[16] = {bv0.x, bv0.y, bv0.z, bv0.w, bv1.x, bv1.y, bv1.z, bv1.w,
                  bv2.x, bv2.y, bv2.z, bv2.w, bv3.x, bv3.y, bv3.z, bv3.w};
  __syncthreads();                          // w3sl/w3dl ready

  // ---- gather phase: 4 dsts per quarter-wave, sequential ----
  for (int it = 0; it < 4; it++){
    int row = it * 16 + rr;
    int d = perm[blockIdx.x * 64 + row];
    if (q == 0) dlds[row] = d;
    int start = row_ptr[d], end = row_ptr[d + 1];
    float a_d = ad_arr[d * 4 + head];
    floatx2 ac[8];
    #pragma unroll
    for (int j = 0; j < 8; j++){ floatx2 z = {0.f, 0.f}; ac[j] = z; }
    float den = 0.f;
    int e = start;
    for (; e + 3 < end; e += 4){
      unsigned s0 = (unsigned)sorted_src[e];
      unsigned s1 = (unsigned)sorted_src[e + 1];
      unsigned s2 = (unsigned)sorted_src[e + 2];
      unsigned s3 = (unsigned)sorted_src[e + 3];
      uint4 v0 = *(const uint4*)(h8 + (((size_t)s0 << 8) | coff));
      uint4 v1 = *(const uint4*)(h8 + (((size_t)s1 << 8) | coff));
      uint4 v2 = *(const uint4*)(h8 + (((size_t)s2 << 8) | coff));
      uint4 v3 = *(const uint4*)(h8 + (((size_t)s3 << 8) | coff));
      float w0 = __expf(lrelu(as_arr[(s0 << 2) + head] + a_d));
      float w1 = __expf(lrelu(as_arr[(s1 << 2) + head] + a_d));
      float w2 = __expf(lrelu(as_arr[(s2 << 2) + head] + a_d));
      float w3 = __expf(lrelu(as_arr[(s3 << 2) + head] + a_d));
      den += (w0 + w1) + (w2 + w3);
      floatx2 W0 = {w0, w0}, W1 = {w1, w1}, W2 = {w2, w2}, W3 = {w3, w3};
      ac[0] += W0 * fp8pk2<false>(v0.x) + W1 * fp8pk2<false>(v1.x)
             + W2 * fp8pk2<false>(v2.x) + W3 * fp8pk2<false>(v3.x);
      ac[1] += W0 * fp8pk2<true>(v0.x)  + W1 * fp8pk2<true>(v1.x)
             + W2 * fp8pk2<true>(v2.x)  + W3 * fp8pk2<true>(v3.x);
      ac[2] += W0 * fp8pk2<false>(v0.y) + W1 * fp8pk2<false>(v1.y)
             + W2 * fp8pk2<false>(v2.y) + W3 * fp8pk2<false>(v3.y);
      ac[3] += W0 * fp8pk2<true>(v0.y)  + W1 * fp8pk2<true>(v1.y)
             + W2 * fp8pk2<true>(v2.y)  + W3 * fp8pk2<true>(v3.y);
      ac[4] += W0 * fp8pk2<false>(v0.z) + W1 * fp8pk2<false>(v1.z)
             + W2 * fp8pk2<false>(v2.z) + W3 * fp8pk2<false>(v3.z);
      ac[5] += W0 * fp8pk2<true>(v0.z)  + W1 * fp8pk2<true>(v1.z)
             + W2 * fp8pk2<true>(v2.z)  + W3 * fp8pk2<true>(v3.z);
      ac[6] += W0 * fp8pk2<false>(v0.w) + W1 * fp8pk2<false>(v1.w)
             + W2 * fp8pk2<false>(v2.w) + W3 * fp8pk2<false>(v3.w);
      ac[7] += W0 * fp8pk2<true>(v0.w)  + W1 * fp8pk2<true>(v1.w)
             + W2 * fp8pk2<true>(v2.w)  + W3 * fp8pk2<true>(v3.w);
    }
    for (; e < end; e++){
      unsigned s = (unsigned)sorted_src[e];
      uint4 v = *(const uint4*)(h8 + (((size_t)s << 8) | coff));
      float wg = __expf(lrelu(as_arr[(s << 2) + head] + a_d));
      den += wg;
      floatx2 wv = {wg, wg};
      ac[0] += wv * fp8pk2<false>(v.x);
      ac[1] += wv * fp8pk2<true>(v.x);
      ac[2] += wv * fp8pk2<false>(v.y);
      ac[3] += wv * fp8pk2<true>(v.y);
      ac[4] += wv * fp8pk2<false>(v.z);
      ac[5] += wv * fp8pk2<true>(v.z);
      ac[6] += wv * fp8pk2<false>(v.w);
      ac[7] += wv * fp8pk2<true>(v.w);
    }
    float inv = 0.015625f / (den + 1e-16f);    // 1/64 undoes fp8 pre-scale
    short8 o0, o1;
    float ps = 0.f, pd = 0.f;
    #pragma unroll
    for (int j = 0; j < 8; j++){
      float v = ((j & 1) ? ac[j >> 1].y : ac[j >> 1].x);
      float h = eluf(v * inv + bb[j]);
      ps += h * w3sl[q * 17 + j];
      pd += h * w3dl[q * 17 + j];
      o0[j] = (short)f2bf(h);
    }
    #pragma unroll
    for (int j = 0; j < 8; j++){
      float v = ((j & 1) ? ac[4 + (j >> 1)].y : ac[4 + (j >> 1)].x);
      float h = eluf(v * inv + bb[8 + j]);
      ps += h * w3sl[q * 17 + 8 + j];
      pd += h * w3dl[q * 17 + 8 + j];
      o1[j] = (short)f2bf(h);
    }
    ps += __shfl_xor(ps, 1, 64); ps += __shfl_xor(ps, 2, 64);
    ps += __shfl_xor(ps, 4, 64); ps += __shfl_xor(ps, 8, 64);
    pd += __shfl_xor(pd, 1, 64); pd += __shfl_xor(pd, 2, 64);
    pd += __shfl_xor(pd, 4, 64); pd += __shfl_xor(pd, 8, 64);
    if (q == 0){ as3[d] = ps; ad3[d] = pd; }
    *(short8*)&hlds[row * LDK + cb] = o0;
    *(short8*)&hlds[row * LDK + cb + 8] = o1;
  }
  __syncthreads();

  // ---- fused GEMM3: wave w owns n-tile w; B-frags loaded once, reused 4x ----
  int r16 = l & 15, quad = l >> 4;
  short8 bfr[8];
  #pragma unroll
  for (int kt = 0; kt < 8; kt++)
    bfr[kt] = *(const short8*)&Wp3[(w * 16 + r16) * 256 + kt * 32 + quad * 8];
  #pragma unroll
  for (int it = 0; it < 4; it++){
    floatx4 acc3 = {0.f, 0.f, 0.f, 0.f};
    #pragma unroll
    for (int kt = 0; kt < 8; kt++){
      short8 af = *(const short8*)&hlds[(it * 16 + r16) * LDK + kt * 32 + quad * 8];
      acc3 = __builtin_amdgcn_mfma_f32_16x16x32_bf16(af, bfr[kt], acc3, 0, 0, 0);
    }
    // C layout: col = w*16 + r16, row = it*16 + quad*4 + r
    unsigned pk = f32x4_to_fp8(acc3[0] * 64.f, acc3[1] * 64.f,
                               acc3[2] * 64.f, acc3[3] * 64.f);
    #pragma unroll
    for (int r = 0; r < 4; r++){
      int row = it * 16 + quad * 4 + r;
      int dd = dlds[row];                   // LDS broadcast (uniform per r16 group)
      h3out[(size_t)dd * 64 + w * 16 + r16] = (unsigned char)((pk >> (r * 8)) & 0xFF);
    }
  }
}

// ---------------- conv3 aggregation (H=1) + fused final FC ----------------
// eighth-wave per dst (R2-proven body); epilogue computes out[d,5] = h3 @ fcw + fcb
// via per-lane partials + 3 shfl_xor — h3 never materialized.

__global__ __launch_bounds__(256) void agg3_k(const unsigned char* __restrict__ h8,
                                              const float* __restrict__ as_arr,
                                              const float* __restrict__ ad_arr,
                                              const int* __restrict__ row_ptr,
                                              const int* __restrict__ sorted_src,
                                              const int* __restrict__ perm,
                                              const float* __restrict__ bias,
                                              const float* __restrict__ fcw,
                                              const float* __restrict__ fcb,
                                              float* __restrict__ out){
  __shared__ float w_lds[320];
  __shared__ float fb5[5];
  int tid = threadIdx.x;
  for (int i = tid; i < 320; i += 256) w_lds[i] = fcw[i];
  if (tid < 5) fb5[tid] = fcb[tid];
  __syncthreads();
  int w = tid >> 6, l = tid & 63;
  int g = l >> 3, q = l & 7;                // group (dst), lane-in-group
  int d = perm[blockIdx.x * 32 + w * 8 + g];
  unsigned coff = (unsigned)(q * 8);        // byte offset in fp8 row
  int start = row_ptr[d], end = row_ptr[d + 1];
  float a_d = ad_arr[d];
  floatx2 ac[4];
  #pragma unroll
  for (int j = 0; j < 4; j++){ floatx2 z = {0.f, 0.f}; ac[j] = z; }
  float den = 0.f;
  int e = start;
  for (; e + 3 < end; e += 4){
    unsigned s0 = (unsigned)sorted_src[e];
    unsigned s1 = (unsigned)sorted_src[e + 1];
    unsigned s2 = (unsigned)sorted_src[e + 2];
    unsigned s3 = (unsigned)sorted_src[e + 3];
    uint2 v0 = *(const uint2*)(h8 + (((size_t)s0 << 6) | coff));
    uint2 v1 = *(const uint2*)(h8 + (((size_t)s1 << 6) | coff));
    uint2 v2 = *(const uint2*)(h8 + (((size_t)s2 << 6) | coff));
    uint2 v3 = *(const uint2*)(h8 + (((size_t)s3 << 6) | coff));
    float w0 = __expf(lrelu(as_arr[s0] + a_d));
    float w1 = __expf(lrelu(as_arr[s1] + a_d));
    float w2 = __expf(lrelu(as_arr[s2] + a_d));
    float w3 = __expf(lrelu(as_arr[s3] + a_d));
    den += (w0 + w1) + (w2 + w3);
    floatx2 W0 = {w0, w0}, W1 = {w1, w1}, W2 = {w2, w2}, W3 = {w3, w3};
    ac[0] += W0 * fp8pk2<false>(v0.x) + W1 * fp8pk2<false>(v1.x)
           + W2 * fp8pk2<false>(v2.x) + W3 * fp8pk2<false>(v3.x);
    ac[1] += W0 * fp8pk2<true>(v0.x)  + W1 * fp8pk2<true>(v1.x)
           + W2 * fp8pk2<true>(v2.x)  + W3 * fp8pk2<true>(v3.x);
    ac[2] += W0 * fp8pk2<false>(v0.y) + W1 * fp8pk2<false>(v1.y)
           + W2 * fp8pk2<false>(v2.y) + W3 * fp8pk2<false>(v3.y);
    ac[3] += W0 * fp8pk2<true>(v0.y)  + W1 * fp8pk2<true>(v1.y)
           + W2 * fp8pk2<true>(v2.y)  + W3 * fp8pk2<true>(v3.y);
  }
  for (; e < end; e++){
    unsigned s = (unsigned)sorted_src[e];
    float wg = __expf(lrelu(as_arr[s] + a_d));
    den += wg;
    uint2 v = *(const uint2*)(h8 + (((size_t)s << 6) | coff));
    floatx2 wv = {wg, wg};
    ac[0] += wv * fp8pk2<false>(v.x);
    ac[1] += wv * fp8pk2<true>(v.x);
    ac[2] += wv * fp8pk2<false>(v.y);
    ac[3] += wv * fp8pk2<true>(v.y);
  }
  float inv = 0.015625f / (den + 1e-16f);    // 1/64 undoes fp8 pre-scale
  int cb = q * 8;
  float4 bA = *(const float4*)&bias[cb];
  float4 bB = *(const float4*)&bias[cb + 4];
  float bb[8] = {bA.x, bA.y, bA.z, bA.w, bB.x, bB.y, bB.z, bB.w};
  float p0 = 0.f, p1 = 0.f, p2 = 0.f, p3 = 0.f, p4 = 0.f;
  #pragma unroll
  for (int j = 0; j < 8; j++){
    float v = ((j & 1) ? ac[j >> 1].y : ac[j >> 1].x);
    float h = eluf(v * inv + bb[j]);
    const float* wr = &w_lds[(cb + j) * 5];
    p0 += h * wr[0];
    p1 += h * wr[1];
    p2 += h * wr[2];
    p3 += h * wr[3];
    p4 += h * wr[4];
  }
  p0 += __shfl_xor(p0, 1, 64); p0 += __shfl_xor(p0, 2, 64); p0 += __shfl_xor(p0, 4, 64);
  p1 += __shfl_xor(p1, 1, 64); p1 += __shfl_xor(p1, 2, 64); p1 += __shfl_xor(p1, 4, 64);
  p2 += __shfl_xor(p2, 1, 64); p2 += __shfl_xor(p2, 2, 64); p2 += __shfl_xor(p2, 4, 64);
  p3 += __shfl_xor(p3, 1, 64); p3 += __shfl_xor(p3, 2, 64); p3 += __shfl_xor(p3, 4, 64);
  p4 += __shfl_xor(p4, 1, 64); p4 += __shfl_xor(p4, 2, 64); p4 += __shfl_xor(p4, 4, 64);
  if (q == 0){
    float* o = out + (size_t)d * 5;
    o[0] = p0 + fb5[0];
    o[1] = p1 + fb5[1];
    o[2] = p2 + fb5[2];
    o[3] = p3 + fb5[3];
    o[4] = p4 + fb5[4];
  }
}

// ---------------- host launch ----------------

extern "C" void kernel_launch(void* const* d_in, const int* in_sizes, int n_in,
                              void* d_out, int out_size, void* d_ws, size_t ws_size,
                              hipStream_t stream){
  const int*   x    = (const int*)d_in[0];
  const int*   ei   = (const int*)d_in[1];
  const float* emb  = (const float*)d_in[2];
  const float* W1   = (const float*)d_in[3];
  const float* a1s  = (const float*)d_in[4];
  const float* a1d  = (const float*)d_in[5];
  const float* b1   = (const float*)d_in[6];
  const float* W2   = (const float*)d_in[7];
  const float* a2s  = (const float*)d_in[8];
  const float* a2d  = (const float*)d_in[9];
  const float* b2   = (const float*)d_in[10];
  const float* W3   = (const float*)d_in[11];
  const float* a3s  = (const float*)d_in[12];
  const float* a3d  = (const float*)d_in[13];
  const float* b3   = (const float*)d_in[14];
  const float* fcw  = (const float*)d_in[15];
  const float* fcb  = (const float*)d_in[16];
  float* out = (float*)d_out;

  const int N = in_sizes[0];
  const int E = in_sizes[1] / 2;
  const int dpb = N / NB;             // dst per bucket (512 for N=131072)
  int shift = 0;
  while ((1 << shift) < dpb) shift++; // log2(dpb)
  const int PB = (E + 4095) / 4096;   // partition blocks

  // workspace partition (256B aligned)
  char* base = (char*)d_ws;
  size_t off = 0;
  auto alloc = [&](size_t bytes) -> void* {
    void* p = base + off;
    off += (bytes + 255) & ~(size_t)255;
    return p;
  };
  unsigned short* bufB    = (unsigned short*)alloc((size_t)N * 256 * 2);  // h1 (conv1 out)
  unsigned char*  buf8    = (unsigned char*)alloc((size_t)N * 256);      // h2 fp8 x64
  unsigned char*  buf8b   = (unsigned char*)alloc((size_t)N * 64);       // h3 fp8 x64
  float* alpha_s          = (float*)alloc((size_t)N * 4 * 4);
  float* alpha_d          = (float*)alloc((size_t)N * 4 * 4);
  float* as3              = (float*)alloc((size_t)N * 4);
  float* ad3              = (float*)alloc((size_t)N * 4);
  int* row_ptr            = (int*)alloc((size_t)(N + 1) * 4);
  int* sorted_src         = (int*)alloc((size_t)(E + N) * 4);
  int* perm               = (int*)alloc((size_t)N * 4);
  uint2* cnt5             = (uint2*)alloc((size_t)N * 8);
  unsigned* bbuf          = (unsigned*)alloc((size_t)NB * CAP * 4);
  int* gcnt               = (int*)alloc((size_t)NB * 4);
  int* gbase              = (int*)alloc((size_t)(NB + 1) * 4);
  float* T1               = (float*)alloc(5 * 256 * 4);
  float* wt_tab           = (float*)alloc(100 * 4);
  float* w3s              = (float*)alloc(256 * 4);
  float* w3d              = (float*)alloc(256 * 4);
  unsigned short* Wp2     = (unsigned short*)alloc(256 * 256 * 2);
  unsigned short* Wp3     = (unsigned short*)alloc(64 * 256 * 2);

  // ---- CSR build (bucket partition) + weight prep, fused ----
  (void)hipMemsetAsync(gcnt, 0, (size_t)NB * 4, stream);
  part_prep_k<<<PB + 321, 256, 0, stream>>>(ei, E, shift, x, gcnt, bbuf, PB,
                                            W2, Wp2, W3, Wp3, emb, W1, a1s, a1d,
                                            a3s, a3d, T1, wt_tab, w3s, w3d);
  bscan_k<<<1, 256, 0, stream>>>(gcnt, gbase, row_ptr, N, dpb);
  sort_k<<<NB, 256, 0, stream>>>(bbuf, gcnt, gbase, x, row_ptr, sorted_src, perm, cnt5, dpb);

  // ---- conv1: histogram aggregation (counts precomputed) -> bufB [N,256] bf16 ----
  agg1_k<<<N / 256, 256, 0, stream>>>(x, T1, wt_tab, cnt5, b1, bufB);

  // ---- conv2: GEMM -> h2 fp8 (x64) + fused head alphas ----
  gemm_lds_k<128, 1, true><<<dim3(N / 128, 2), 256, 0, stream>>>(bufB, Wp2, buf8, 256,
                                                                 a2s, a2d, alpha_s, alpha_d);
  // ---- conv2 aggregation + FUSED conv3 GEMM (64 dsts/block) ----
  agg4g_k<<<N / 64, 256, 0, stream>>>(buf8, alpha_s, alpha_d, row_ptr, sorted_src, perm, b2,
                                      Wp3, w3s, w3d, buf8b, as3, ad3);

  // ---- conv3 aggregation + fused final FC -> d_out [N,5] f32 ----
  agg3_k<<<N / 32, 256, 0, stream>>>(buf8b, as3, ad3, row_ptr, sorted_src, perm, b3,
                                     fcw, fcb, out);
}

// Round 10
// 308.340 us; speedup vs baseline: 1.0329x; 1.0329x over previous
//
#include <hip/hip_runtime.h>
#include <hip/hip_bf16.h>
#include <hip/hip_fp8.h>

typedef __attribute__((ext_vector_type(8))) short short8;
typedef __attribute__((ext_vector_type(4))) short short4_t;
typedef __attribute__((ext_vector_type(4))) float floatx4;
typedef __attribute__((ext_vector_type(2))) float floatx2;

constexpr int NB  = 256;    // dst buckets
constexpr int CAP = 6144;   // pairs per bucket (mean 4096 for uniform graph)

__device__ __forceinline__ unsigned short f2bf(float f){
  unsigned int u = __float_as_uint(f);
  u += 0x7FFF + ((u >> 16) & 1);           // RNE
  return (unsigned short)(u >> 16);
}
__device__ __forceinline__ float bf2f(unsigned short h){
  return __uint_as_float(((unsigned int)h) << 16);
}
__device__ __forceinline__ float lrelu(float x){ return x > 0.f ? x : 0.2f * x; }
__device__ __forceinline__ float eluf(float x){ return x > 0.f ? x : (__expf(x) - 1.f); }

__device__ __forceinline__ unsigned char f2fp8(float f){
  __hip_fp8_e4m3 t(f);
  return (unsigned char)t.__x;
}
__device__ __forceinline__ float fp82f(unsigned char b){
  __hip_fp8_e4m3 t;
  t.__x = (__hip_fp8_storage_t)b;
  return (float)t;
}

template<bool HI>
__device__ __forceinline__ floatx2 fp8pk2(unsigned int v){
#if defined(__has_builtin) && __has_builtin(__builtin_amdgcn_cvt_pk_f32_fp8)
  return __builtin_amdgcn_cvt_pk_f32_fp8((int)v, HI);
#else
  floatx2 r;
  constexpr int sh = HI ? 16 : 0;
  r.x = fp82f((unsigned char)((v >> sh) & 0xFF));
  r.y = fp82f((unsigned char)((v >> (sh + 8)) & 0xFF));
  return r;
#endif
}

// HW packed fp8 encode of 4 floats -> 4 bytes (returned in uint, b0..b3)
__device__ __forceinline__ unsigned int f32x4_to_fp8(float a0, float a1, float a2, float a3){
#if defined(__has_builtin) && __has_builtin(__builtin_amdgcn_cvt_pk_fp8_f32)
  int w = 0;
  w = __builtin_amdgcn_cvt_pk_fp8_f32(a0, a1, w, false);   // bytes 0,1
  w = __builtin_amdgcn_cvt_pk_fp8_f32(a2, a3, w, true);    // bytes 2,3
  return (unsigned int)w;
#else
  return (unsigned int)f2fp8(a0) | ((unsigned int)f2fp8(a1) << 8) |
         ((unsigned int)f2fp8(a2) << 16) | ((unsigned int)f2fp8(a3) << 24);
#endif
}

// chunk-stratified scramble of sorted rank p in [0,512):
// 64 consecutive ranks (one agg4g block) stay together -> degree-uniform
// blocks (cheap intra-block barrier); chunk order rotated -> grid balance.
__device__ __forceinline__ int scr512(int p){
  int c = p >> 6, s = p & 63;              // 8 chunks of 64
  int cc = ((c & 3) << 1) | (c >> 2);      // rotate-left-1 of 3-bit chunk id
  return (cc << 6) | s;
}

// async global->LDS, 16B per lane; LDS dest = base + lane*16
__device__ __forceinline__ void gload16(const unsigned short* g, unsigned short* l){
  __builtin_amdgcn_global_load_lds(
      (const __attribute__((address_space(1))) unsigned int*)(const void*)g,
      (__attribute__((address_space(3))) unsigned int*)(void*)l,
      16, 0, 0);
}

// ---------------- fused: edge bucket-partition + weight prep (independent work) ----------------
// bbuf word packing: src (17b) | ldst (9b, <<17) | x[src] (3b, <<26)
__global__ __launch_bounds__(256) void part_prep_k(const int* __restrict__ ei, int E, int shift,
                                                   const int* __restrict__ x,
                                                   int* __restrict__ gcnt,
                                                   unsigned* __restrict__ bbuf, int PB,
                                                   const float* __restrict__ W2,
                                                   unsigned short* __restrict__ Wp2,
                                                   const float* __restrict__ W3,
                                                   unsigned short* __restrict__ Wp3,
                                                   const float* __restrict__ emb,
                                                   const float* __restrict__ W1,
                                                   const float* __restrict__ a1s,
                                                   const float* __restrict__ a1d,
                                                   float* __restrict__ T1,
                                                   float* __restrict__ wt_tab){
  int blk = blockIdx.x;
  int tid = threadIdx.x;
  if (blk < PB){
    __shared__ int hist[NB];
    __shared__ int base[NB];
    hist[tid] = 0;
    __syncthreads();
    int blk_start = blk * 4096;
    int ldmask = (1 << shift) - 1;
    unsigned word[16];
    int bkt[16], lp[16];
    #pragma unroll
    for (int k = 0; k < 16; k++){
      int i = blk_start + k * 256 + tid;
      if (i < E){
        int dst = ei[E + i];
        int s = ei[i];
        int xs = x[s];                       // 512KB table, L2-resident
        bkt[k] = dst >> shift;
        word[k] = (unsigned)s | ((unsigned)(dst & ldmask) << 17) | ((unsigned)xs << 26);
        lp[k] = atomicAdd(&hist[bkt[k]], 1);
      } else {
        bkt[k] = -1;
      }
    }
    __syncthreads();
    base[tid] = atomicAdd(&gcnt[tid], hist[tid]);
    __syncthreads();
    #pragma unroll
    for (int k = 0; k < 16; k++){
      if (bkt[k] >= 0){
        int b = bkt[k];
        bbuf[(size_t)b * CAP + base[b] + lp[k]] = word[k];
      }
    }
    return;
  }
  int b = blk - PB;
  if (b < 256){                      // W2 [256,256] -> Wp2[n*256+k]
    int idx = b * 256 + tid;
    int k = idx >> 8, nn = idx & 255;
    Wp2[nn * 256 + k] = f2bf(W2[idx]);
  } else if (b < 320){               // W3 [256,64] -> Wp3[n*256+k]
    int idx = (b - 256) * 256 + tid;
    int k = idx >> 6, nn = idx & 63;
    Wp3[nn * 256 + k] = f2bf(W3[idx]);
  } else {                           // conv1 tables
    __shared__ float t_lds[1280];
    __shared__ float as_l[20], ad_l[20];
    for (int i = tid; i < 1280; i += 256){
      int r = i >> 8, c = i & 255;
      float s = 0.f;
      for (int k = 0; k < 64; k++) s += emb[r * 64 + k] * W1[k * 256 + c];
      t_lds[i] = s;
      T1[i] = s;
    }
    __syncthreads();
    if (tid < 20){
      int r = tid >> 2, hh = tid & 3;
      float ss = 0.f, sd = 0.f;
      for (int c = 0; c < 64; c++){
        float f = t_lds[r * 256 + hh * 64 + c];
        ss += f * a1s[hh * 64 + c];
        sd += f * a1d[hh * 64 + c];
      }
      as_l[tid] = ss;
      ad_l[tid] = sd;
    }
    __syncthreads();
    if (tid < 100){
      int xd = tid / 20, rest = tid % 20;      // rest = xs*4+h
      int h = rest & 3;
      wt_tab[tid] = __expf(lrelu(as_l[rest] + ad_l[xd * 4 + h]));
    }
  }
}

__global__ __launch_bounds__(256) void bscan_k(const int* __restrict__ gcnt,
                                               int* __restrict__ gbase,
                                               int* __restrict__ row_ptr, int N, int dpb){
  __shared__ int s[NB];
  int t = threadIdx.x;
  int v = gcnt[t] + dpb;
  s[t] = v;
  __syncthreads();
  #pragma unroll
  for (int off = 1; off < NB; off <<= 1){
    int u = (t >= off) ? s[t - off] : 0;
    __syncthreads();
    s[t] += u;
    __syncthreads();
  }
  gbase[t] = s[t] - v;
  if (t == NB - 1){ gbase[NB] = s[t]; row_ptr[N] = s[t]; }
}

// sort packed words into CSR; emit degree-sorted chunk-stratified perm AND the
// per-dst 5-bin x-value histogram (cnt5, packed u8x5 in a uint2) for conv1.
__global__ __launch_bounds__(256) void sort_k(const unsigned* __restrict__ bbuf,
                                              const int* __restrict__ gcnt,
                                              const int* __restrict__ gbase,
                                              const int* __restrict__ x,
                                              int* __restrict__ row_ptr,
                                              int* __restrict__ sorted_src,
                                              int* __restrict__ perm,
                                              uint2* __restrict__ cnt5, int dpb){
  __shared__ int counts[512];
  __shared__ int curs[512];
  __shared__ int wsum[256];
  __shared__ int sortedL[CAP + 512];
  __shared__ int dh[64];
  __shared__ int h5[512 * 5];
  int b = blockIdx.x, tid = threadIdx.x;
  int cnt = gcnt[b];
  int dstBase = b * dpb;
  int gb = gbase[b];
  counts[tid] = 0;
  counts[tid + 256] = 0;
  for (int i = tid; i < dpb * 5; i += 256) h5[i] = 0;
  __syncthreads();
  for (int i = tid; i < cnt; i += 256){
    unsigned pw = bbuf[(size_t)b * CAP + i];
    atomicAdd(&counts[(pw >> 17) & (dpb - 1)], 1);
  }
  // self-loop x-values (each dst's own x counts once)
  {
    int x0 = x[dstBase + 2 * tid];
    int x1 = x[dstBase + 2 * tid + 1];
    atomicAdd(&h5[(2 * tid) * 5 + x0], 1);
    atomicAdd(&h5[(2 * tid + 1) * 5 + x1], 1);
  }
  __syncthreads();
  int c0 = counts[2 * tid] + 1;
  int c1 = counts[2 * tid + 1] + 1;
  int sum = c0 + c1;
  wsum[tid] = sum;
  __syncthreads();
  #pragma unroll
  for (int off = 1; off < 256; off <<= 1){
    int u = (tid >= off) ? wsum[tid - off] : 0;
    __syncthreads();
    wsum[tid] += u;
    __syncthreads();
  }
  int ex = wsum[tid] - sum;
  int ro0 = ex, ro1 = ex + c0;
  curs[2 * tid] = ro0 + 1;          // slot ro reserved for self-loop
  curs[2 * tid + 1] = ro1 + 1;
  sortedL[ro0] = dstBase + 2 * tid;
  sortedL[ro1] = dstBase + 2 * tid + 1;
  row_ptr[dstBase + 2 * tid] = gb + ro0;
  row_ptr[dstBase + 2 * tid + 1] = gb + ro1;
  __syncthreads();
  for (int i = tid; i < cnt; i += 256){
    unsigned pw = bbuf[(size_t)b * CAP + i];
    int ldst = (pw >> 17) & (dpb - 1);
    int pos = atomicAdd(&curs[ldst], 1);
    sortedL[pos] = (int)(pw & 0x1FFFF);
    atomicAdd(&h5[ldst * 5 + (pw >> 26)], 1);
  }
  __syncthreads();
  int tot = cnt + dpb;
  for (int i = tid; i < tot; i += 256) sorted_src[gb + i] = sortedL[i];

  // pack per-dst 5-bin counts: bytes v0..v3 in .x, v4 in .y
  {
    int d0 = 2 * tid, d1 = 2 * tid + 1;
    unsigned lo0 = (unsigned)h5[d0 * 5 + 0] | ((unsigned)h5[d0 * 5 + 1] << 8) |
                   ((unsigned)h5[d0 * 5 + 2] << 16) | ((unsigned)h5[d0 * 5 + 3] << 24);
    unsigned lo1 = (unsigned)h5[d1 * 5 + 0] | ((unsigned)h5[d1 * 5 + 1] << 8) |
                   ((unsigned)h5[d1 * 5 + 2] << 16) | ((unsigned)h5[d1 * 5 + 3] << 24);
    cnt5[dstBase + d0] = make_uint2(lo0, (unsigned)h5[d0 * 5 + 4]);
    cnt5[dstBase + d1] = make_uint2(lo1, (unsigned)h5[d1 * 5 + 4]);
  }

  // ---- degree-sorted permutation (counting sort, 64 bins), chunk-stratified ----
  __syncthreads();
  if (tid < 64) dh[tid] = 0;
  __syncthreads();
  int dg0 = c0 < 63 ? c0 : 63;
  int dg1 = c1 < 63 ? c1 : 63;
  int r0 = atomicAdd(&dh[dg0], 1);
  int r1 = atomicAdd(&dh[dg1], 1);
  __syncthreads();
  if (tid == 0){
    int run = 0;
    for (int i = 0; i < 64; i++){ int c = dh[i]; dh[i] = run; run += c; }
  }
  __syncthreads();
  perm[dstBase + scr512(dh[dg0] + r0)] = dstBase + 2 * tid;
  perm[dstBase + scr512(dh[dg1] + r1)] = dstBase + 2 * tid + 1;
}

// ---------------- LDS-staged MFMA GEMM, fused alpha epilogues ----------------
template<int BN, int MODE, bool F8OUT>
__global__ __launch_bounds__(256) void gemm_lds_k(const unsigned short* __restrict__ A,
                                                  const unsigned short* __restrict__ Wp,
                                                  void* __restrict__ Cout, int Nc,
                                                  const float* __restrict__ a_src,
                                                  const float* __restrict__ a_dst,
                                                  float* __restrict__ as_arr,
                                                  float* __restrict__ ad_arr){
  constexpr int K = 256;
  constexpr int NT = BN / 32;               // col tiles per wave (4 or 2)
  __shared__ unsigned short Alds[128 * 32];
  __shared__ unsigned short Blds[BN * 32];
  __shared__ float asl[128], adl[128];
  __shared__ float pas[128][2], pad[128][2];
  int tid = threadIdx.x;
  int w = tid >> 6, l = tid & 63;
  int r16 = l & 15, quad = l >> 4;
  int wr = w >> 1, wc = w & 1;
  int mBase = blockIdx.x * 128;
  int nBase = blockIdx.y * BN;

  if constexpr (MODE == 1){
    if (tid < 128){ asl[tid] = a_src[nBase + tid]; adl[tid] = a_dst[nBase + tid]; }
  }
  if constexpr (MODE == 2){
    if (tid < 64){ asl[tid] = a_src[tid]; adl[tid] = a_dst[tid]; }
  }

  int arow = l >> 2;
  int kcol = (l & 3) * 8;                   // shorts
  const unsigned short* gA0 = A + (size_t)(mBase + w * 32 + arow) * K + kcol;
  const unsigned short* gA1 = gA0 + (size_t)16 * K;
  unsigned short* lA0 = &Alds[(w * 32) * 32];
  unsigned short* lA1 = &Alds[(w * 32 + 16) * 32];
  const unsigned short* gB0;
  const unsigned short* gB1 = nullptr;
  unsigned short* lB0;
  unsigned short* lB1 = nullptr;
  if constexpr (BN == 128){
    gB0 = Wp + (size_t)(nBase + w * 32 + arow) * K + kcol;
    gB1 = gB0 + (size_t)16 * K;
    lB0 = &Blds[(w * 32) * 32];
    lB1 = &Blds[(w * 32 + 16) * 32];
  } else {
    gB0 = Wp + (size_t)(nBase + w * 16 + arow) * K + kcol;
    lB0 = &Blds[(w * 16) * 32];
  }

  floatx4 acc[4][NT];
  #pragma unroll
  for (int mt = 0; mt < 4; mt++)
    #pragma unroll
    for (int nt = 0; nt < NT; nt++){ floatx4 z = {0.f,0.f,0.f,0.f}; acc[mt][nt] = z; }

  for (int kt = 0; kt < 8; kt++){
    int ko = kt * 32;
    gload16(gA0 + ko, lA0);
    gload16(gA1 + ko, lA1);
    gload16(gB0 + ko, lB0);
    if constexpr (BN == 128) gload16(gB1 + ko, lB1);
    __syncthreads();
    short8 af[4], bfr[NT];
    #pragma unroll
    for (int mt = 0; mt < 4; mt++)
      af[mt] = *(const short8*)&Alds[(wr * 64 + mt * 16 + r16) * 32 + quad * 8];
    #pragma unroll
    for (int nt = 0; nt < NT; nt++)
      bfr[nt] = *(const short8*)&Blds[(wc * (BN / 2) + nt * 16 + r16) * 32 + quad * 8];
    #pragma unroll
    for (int mt = 0; mt < 4; mt++)
      #pragma unroll
      for (int nt = 0; nt < NT; nt++)
        acc[mt][nt] = __builtin_amdgcn_mfma_f32_16x16x32_bf16(af[mt], bfr[nt], acc[mt][nt], 0, 0, 0);
    __syncthreads();
  }

  // epilogue: C/D layout col=lane&15, row=quad*4+reg
  #pragma unroll
  for (int mt = 0; mt < 4; mt++){
    #pragma unroll
    for (int nt = 0; nt < NT; nt++){
      if constexpr (F8OUT){
        unsigned int pk = f32x4_to_fp8(acc[mt][nt][0] * 64.f, acc[mt][nt][1] * 64.f,
                                       acc[mt][nt][2] * 64.f, acc[mt][nt][3] * 64.f);
        int col = nBase + wc * (BN / 2) + nt * 16 + r16;
        int row0 = mBase + wr * 64 + mt * 16 + quad * 4;
        #pragma unroll
        for (int r = 0; r < 4; r++)
          ((unsigned char*)Cout)[(size_t)(row0 + r) * Nc + col] =
              (unsigned char)((pk >> (r * 8)) & 0xFF);
      } else {
        #pragma unroll
        for (int r = 0; r < 4; r++){
          int row = mBase + wr * 64 + mt * 16 + quad * 4 + r;
          int col = nBase + wc * (BN / 2) + nt * 16 + r16;
          ((unsigned short*)Cout)[(size_t)row * Nc + col] = f2bf(acc[mt][nt][r]);
        }
      }
    }
  }
  if constexpr (MODE == 1){
    int head = (nBase + wc * 64) >> 6;
    #pragma unroll
    for (int mt = 0; mt < 4; mt++){
      #pragma unroll
      for (int r = 0; r < 4; r++){
        float ps = 0.f, pd = 0.f;
        #pragma unroll
        for (int nt = 0; nt < NT; nt++){
          float v = acc[mt][nt][r];
          int ci = wc * 64 + nt * 16 + r16;
          ps += v * asl[ci];
          pd += v * adl[ci];
        }
        ps += __shfl_xor(ps, 1, 64); ps += __shfl_xor(ps, 2, 64);
        ps += __shfl_xor(ps, 4, 64); ps += __shfl_xor(ps, 8, 64);
        pd += __shfl_xor(pd, 1, 64); pd += __shfl_xor(pd, 2, 64);
        pd += __shfl_xor(pd, 4, 64); pd += __shfl_xor(pd, 8, 64);
        if (r16 == 0){
          int row = mBase + wr * 64 + mt * 16 + quad * 4 + r;
          as_arr[row * 4 + head] = ps;
          ad_arr[row * 4 + head] = pd;
        }
      }
    }
  }
  if constexpr (MODE == 2){
    #pragma unroll
    for (int mt = 0; mt < 4; mt++){
      #pragma unroll
      for (int r = 0; r < 4; r++){
        float ps = 0.f, pd = 0.f;
        #pragma unroll
        for (int nt = 0; nt < NT; nt++){
          float v = acc[mt][nt][r];
          int ci = wc * 32 + nt * 16 + r16;
          ps += v * asl[ci];
          pd += v * adl[ci];
        }
        ps += __shfl_xor(ps, 1, 64); ps += __shfl_xor(ps, 2, 64);
        ps += __shfl_xor(ps, 4, 64); ps += __shfl_xor(ps, 8, 64);
        pd += __shfl_xor(pd, 1, 64); pd += __shfl_xor(pd, 2, 64);
        pd += __shfl_xor(pd, 4, 64); pd += __shfl_xor(pd, 8, 64);
        if (r16 == 0){
          int lr = wr * 64 + mt * 16 + quad * 4 + r;
          pas[lr][wc] = ps;
          pad[lr][wc] = pd;
        }
      }
    }
    __syncthreads();
    if (tid < 128){
      as_arr[mBase + tid] = pas[tid][0] + pas[tid][1];
      ad_arr[mBase + tid] = pad[tid][0] + pad[tid][1];
    }
  }
}

// ---------------- conv1 aggregation: counts precomputed in sort_k ----------------

__global__ __launch_bounds__(256) void agg1_k(const int* __restrict__ x,
                                              const float* __restrict__ T1,
                                              const float* __restrict__ wt_tab,
                                              const uint2* __restrict__ cnt5,
                                              const float* __restrict__ bias,
                                              unsigned short* __restrict__ outb){
  __shared__ float t_lds[1280];
  __shared__ float wt_l[100], b_lds[256];
  __shared__ float cnt_lds[256][5];
  __shared__ int xd_lds[256];
  int tid = threadIdx.x;
  for (int i = tid; i < 1280; i += 256) t_lds[i] = T1[i];
  if (tid < 100) wt_l[tid] = wt_tab[tid];
  b_lds[tid] = bias[tid];
  int d = blockIdx.x * 256 + tid;
  uint2 cw = cnt5[d];
  xd_lds[tid] = x[d];
  cnt_lds[tid][0] = (float)(cw.x & 0xFF);
  cnt_lds[tid][1] = (float)((cw.x >> 8) & 0xFF);
  cnt_lds[tid][2] = (float)((cw.x >> 16) & 0xFF);
  cnt_lds[tid][3] = (float)(cw.x >> 24);
  cnt_lds[tid][4] = (float)(cw.y & 0xFF);
  __syncthreads();
  // wave per dst, lane covers 4 channels
  int w = tid >> 6, l = tid & 63;
  int head = l >> 4;
  int c0i = l * 4;
  for (int dl = w; dl < 256; dl += 4){
    int dd = blockIdx.x * 256 + dl;
    int xd20 = xd_lds[dl] * 20;
    float ws[5];
    float den = 0.f;
    #pragma unroll
    for (int v2 = 0; v2 < 5; v2++){
      float wv = wt_l[xd20 + v2 * 4 + head] * cnt_lds[dl][v2];
      ws[v2] = wv;
      den += wv;
    }
    float inv = 1.f / (den + 1e-16f);
    float num[4] = {0.f, 0.f, 0.f, 0.f};
    #pragma unroll
    for (int v2 = 0; v2 < 5; v2++){
      const float4 row = *(const float4*)&t_lds[v2 * 256 + c0i];
      num[0] += ws[v2] * row.x;
      num[1] += ws[v2] * row.y;
      num[2] += ws[v2] * row.z;
      num[3] += ws[v2] * row.w;
    }
    short4_t ov;
    #pragma unroll
    for (int j = 0; j < 4; j++)
      ov[j] = (short)f2bf(eluf(num[j] * inv + b_lds[c0i + j]));
    *(short4_t*)(outb + (size_t)dd * 256 + c0i) = ov;
  }
}

// ---------------- conv2 aggregation + FUSED conv3 GEMM (64 dsts/block) ----------------
// Quarter-wave per dst, 4 dsts sequentially per quarter-wave -> 4x longer gather
// bursts between barriers. ONE barrier, then 4 MFMA row-tiles with W3 B-frags
// loaded into registers once (reused 4x). R8-verified best form (88.6 us).

__global__ __launch_bounds__(256) void agg4g_k(const unsigned char* __restrict__ h8,
                                               const float* __restrict__ as_arr,
                                               const float* __restrict__ ad_arr,
                                               const int* __restrict__ row_ptr,
                                               const int* __restrict__ sorted_src,
                                               const int* __restrict__ perm,
                                               const float* __restrict__ bias,
                                               const unsigned short* __restrict__ Wp3,
                                               const float* __restrict__ a3s,
                                               const float* __restrict__ a3d,
                                               unsigned char* __restrict__ h3out,
                                               float* __restrict__ as3,
                                               float* __restrict__ ad3){
  constexpr int LDK = 264;                  // 256 + 8 pad (bank-spread)
  __shared__ unsigned short hlds[64 * LDK]; // 33.8 KB
  __shared__ float pasl[64][4], padl[64][4];
  __shared__ unsigned char h3st[64 * 64];
  __shared__ int dlds[64];
  int tid = threadIdx.x;
  int w = tid >> 6, l = tid & 63;
  int g = l >> 4, q = l & 15;               // group (dst), lane-in-group
  int rr = w * 4 + g;                       // row within 16-row group
  unsigned coff = (unsigned)(q * 16);       // byte offset in fp8 row
  int head = q >> 2;
  int cb = q * 16;
  float4 bv0 = *(const float4*)&bias[cb];
  float4 bv1 = *(const float4*)&bias[cb + 4];
  float4 bv2 = *(const float4*)&bias[cb + 8];
  float4 bv3 = *(const float4*)&bias[cb + 12];
  float bb[16] = {bv0.x, bv0.y, bv0.z, bv0.w, bv1.x, bv1.y, bv1.z, bv1.w,
                  bv2.x, bv2.y, bv2.z, bv2.w, bv3.x, bv3.y, bv3.z, bv3.w};

  // ---- gather phase: 4 dsts per quarter-wave, sequential ----
  for (int it = 0; it < 4; it++){
    int row = it * 16 + rr;
    int d = perm[blockIdx.x * 64 + row];
    if (q == 0) dlds[row] = d;
    int start = row_ptr[d], end = row_ptr[d + 1];
    float a_d = ad_arr[d * 4 + head];
    floatx2 ac[8];
    #pragma unroll
    for (int j = 0; j < 8; j++){ floatx2 z = {0.f, 0.f}; ac[j] = z; }
    float den = 0.f;
    int e = start;
    for (; e + 3 < end; e += 4){
      unsigned s0 = (unsigned)sorted_src[e];
      unsigned s1 = (unsigned)sorted_src[e + 1];
      unsigned s2 = (unsigned)sorted_src[e + 2];
      unsigned s3 = (unsigned)sorted_src[e + 3];
      uint4 v0 = *(const uint4*)(h8 + (((size_t)s0 << 8) | coff));
      uint4 v1 = *(const uint4*)(h8 + (((size_t)s1 << 8) | coff));
      uint4 v2 = *(const uint4*)(h8 + (((size_t)s2 << 8) | coff));
      uint4 v3 = *(const uint4*)(h8 + (((size_t)s3 << 8) | coff));
      float w0 = __expf(lrelu(as_arr[(s0 << 2) + head] + a_d));
      float w1 = __expf(lrelu(as_arr[(s1 << 2) + head] + a_d));
      float w2 = __expf(lrelu(as_arr[(s2 << 2) + head] + a_d));
      float w3 = __expf(lrelu(as_arr[(s3 << 2) + head] + a_d));
      den += (w0 + w1) + (w2 + w3);
      floatx2 W0 = {w0, w0}, W1 = {w1, w1}, W2 = {w2, w2}, W3 = {w3, w3};
      ac[0] += W0 * fp8pk2<false>(v0.x) + W1 * fp8pk2<false>(v1.x)
             + W2 * fp8pk2<false>(v2.x) + W3 * fp8pk2<false>(v3.x);
      ac[1] += W0 * fp8pk2<true>(v0.x)  + W1 * fp8pk2<true>(v1.x)
             + W2 * fp8pk2<true>(v2.x)  + W3 * fp8pk2<true>(v3.x);
      ac[2] += W0 * fp8pk2<false>(v0.y) + W1 * fp8pk2<false>(v1.y)
             + W2 * fp8pk2<false>(v2.y) + W3 * fp8pk2<false>(v3.y);
      ac[3] += W0 * fp8pk2<true>(v0.y)  + W1 * fp8pk2<true>(v1.y)
             + W2 * fp8pk2<true>(v2.y)  + W3 * fp8pk2<true>(v3.y);
      ac[4] += W0 * fp8pk2<false>(v0.z) + W1 * fp8pk2<false>(v1.z)
             + W2 * fp8pk2<false>(v2.z) + W3 * fp8pk2<false>(v3.z);
      ac[5] += W0 * fp8pk2<true>(v0.z)  + W1 * fp8pk2<true>(v1.z)
             + W2 * fp8pk2<true>(v2.z)  + W3 * fp8pk2<true>(v3.z);
      ac[6] += W0 * fp8pk2<false>(v0.w) + W1 * fp8pk2<false>(v1.w)
             + W2 * fp8pk2<false>(v2.w) + W3 * fp8pk2<false>(v3.w);
      ac[7] += W0 * fp8pk2<true>(v0.w)  + W1 * fp8pk2<true>(v1.w)
             + W2 * fp8pk2<true>(v2.w)  + W3 * fp8pk2<true>(v3.w);
    }
    for (; e < end; e++){
      unsigned s = (unsigned)sorted_src[e];
      uint4 v = *(const uint4*)(h8 + (((size_t)s << 8) | coff));
      float wg = __expf(lrelu(as_arr[(s << 2) + head] + a_d));
      den += wg;
      floatx2 wv = {wg, wg};
      ac[0] += wv * fp8pk2<false>(v.x);
      ac[1] += wv * fp8pk2<true>(v.x);
      ac[2] += wv * fp8pk2<false>(v.y);
      ac[3] += wv * fp8pk2<true>(v.y);
      ac[4] += wv * fp8pk2<false>(v.z);
      ac[5] += wv * fp8pk2<true>(v.z);
      ac[6] += wv * fp8pk2<false>(v.w);
      ac[7] += wv * fp8pk2<true>(v.w);
    }
    float inv = 0.015625f / (den + 1e-16f);    // 1/64 undoes fp8 pre-scale
    short8 o0, o1;
    #pragma unroll
    for (int j = 0; j < 8; j++){
      float v = ((j & 1) ? ac[j >> 1].y : ac[j >> 1].x);
      o0[j] = (short)f2bf(eluf(v * inv + bb[j]));
    }
    #pragma unroll
    for (int j = 0; j < 8; j++){
      float v = ((j & 1) ? ac[4 + (j >> 1)].y : ac[4 + (j >> 1)].x);
      o1[j] = (short)f2bf(eluf(v * inv + bb[8 + j]));
    }
    *(short8*)&hlds[row * LDK + cb] = o0;
    *(short8*)&hlds[row * LDK + cb + 8] = o1;
  }
  __syncthreads();

  // ---- fused GEMM3: wave w owns n-tile w; B-frags loaded once, reused 4x ----
  int r16 = l & 15, quad = l >> 4;
  short8 bfr[8];
  #pragma unroll
  for (int kt = 0; kt < 8; kt++)
    bfr[kt] = *(const short8*)&Wp3[(w * 16 + r16) * 256 + kt * 32 + quad * 8];
  float a3sv = a3s[w * 16 + r16];
  float a3dv = a3d[w * 16 + r16];
  #pragma unroll
  for (int it = 0; it < 4; it++){
    floatx4 acc3 = {0.f, 0.f, 0.f, 0.f};
    #pragma unroll
    for (int kt = 0; kt < 8; kt++){
      short8 af = *(const short8*)&hlds[(it * 16 + r16) * LDK + kt * 32 + quad * 8];
      acc3 = __builtin_amdgcn_mfma_f32_16x16x32_bf16(af, bfr[kt], acc3, 0, 0, 0);
    }
    // C layout: col = w*16 + r16, row = it*16 + quad*4 + reg
    float ps[4], pd[4];
    #pragma unroll
    for (int r = 0; r < 4; r++){
      ps[r] = acc3[r] * a3sv;
      pd[r] = acc3[r] * a3dv;
      ps[r] += __shfl_xor(ps[r], 1, 64); ps[r] += __shfl_xor(ps[r], 2, 64);
      ps[r] += __shfl_xor(ps[r], 4, 64); ps[r] += __shfl_xor(ps[r], 8, 64);
      pd[r] += __shfl_xor(pd[r], 1, 64); pd[r] += __shfl_xor(pd[r], 2, 64);
      pd[r] += __shfl_xor(pd[r], 4, 64); pd[r] += __shfl_xor(pd[r], 8, 64);
      h3st[(it * 16 + quad * 4 + r) * 64 + w * 16 + r16] = f2fp8(acc3[r] * 64.f);
    }
    if (r16 == 0){
      #pragma unroll
      for (int r = 0; r < 4; r++){
        pasl[it * 16 + quad * 4 + r][w] = ps[r];
        padl[it * 16 + quad * 4 + r][w] = pd[r];
      }
    }
  }
  __syncthreads();
  // transpose-out: 64 rows x 16 dwords = 1024 dwords, 4 per thread (coalesced)
  #pragma unroll
  for (int k2 = 0; k2 < 4; k2++){
    int idx = k2 * 256 + tid;
    int row = idx >> 4, c4 = idx & 15;
    unsigned v = *(const unsigned*)&h3st[row * 64 + c4 * 4];
    int dd = dlds[row];
    *(unsigned*)(h3out + (size_t)dd * 64 + c4 * 4) = v;
    if (c4 == 0){
      as3[dd] = pasl[row][0] + pasl[row][1] + pasl[row][2] + pasl[row][3];
      ad3[dd] = padl[row][0] + padl[row][1] + padl[row][2] + padl[row][3];
    }
  }
}

// ---------------- conv3 aggregation (H=1) + fused final FC ----------------
// eighth-wave per dst (R2-proven body); epilogue computes out[d,5] = h3 @ fcw + fcb
// via per-lane partials + 3 shfl_xor — h3 never materialized.

__global__ __launch_bounds__(256) void agg3_k(const unsigned char* __restrict__ h8,
                                              const float* __restrict__ as_arr,
                                              const float* __restrict__ ad_arr,
                                              const int* __restrict__ row_ptr,
                                              const int* __restrict__ sorted_src,
                                              const int* __restrict__ perm,
                                              const float* __restrict__ bias,
                                              const float* __restrict__ fcw,
                                              const float* __restrict__ fcb,
                                              float* __restrict__ out){
  __shared__ float w_lds[320];
  __shared__ float fb5[5];
  int tid = threadIdx.x;
  for (int i = tid; i < 320; i += 256) w_lds[i] = fcw[i];
  if (tid < 5) fb5[tid] = fcb[tid];
  __syncthreads();
  int w = tid >> 6, l = tid & 63;
  int g = l >> 3, q = l & 7;                // group (dst), lane-in-group
  int d = perm[blockIdx.x * 32 + w * 8 + g];
  unsigned coff = (unsigned)(q * 8);        // byte offset in fp8 row
  int start = row_ptr[d], end = row_ptr[d + 1];
  float a_d = ad_arr[d];
  floatx2 ac[4];
  #pragma unroll
  for (int j = 0; j < 4; j++){ floatx2 z = {0.f, 0.f}; ac[j] = z; }
  float den = 0.f;
  int e = start;
  for (; e + 3 < end; e += 4){
    unsigned s0 = (unsigned)sorted_src[e];
    unsigned s1 = (unsigned)sorted_src[e + 1];
    unsigned s2 = (unsigned)sorted_src[e + 2];
    unsigned s3 = (unsigned)sorted_src[e + 3];
    uint2 v0 = *(const uint2*)(h8 + (((size_t)s0 << 6) | coff));
    uint2 v1 = *(const uint2*)(h8 + (((size_t)s1 << 6) | coff));
    uint2 v2 = *(const uint2*)(h8 + (((size_t)s2 << 6) | coff));
    uint2 v3 = *(const uint2*)(h8 + (((size_t)s3 << 6) | coff));
    float w0 = __expf(lrelu(as_arr[s0] + a_d));
    float w1 = __expf(lrelu(as_arr[s1] + a_d));
    float w2 = __expf(lrelu(as_arr[s2] + a_d));
    float w3 = __expf(lrelu(as_arr[s3] + a_d));
    den += (w0 + w1) + (w2 + w3);
    floatx2 W0 = {w0, w0}, W1 = {w1, w1}, W2 = {w2, w2}, W3 = {w3, w3};
    ac[0] += W0 * fp8pk2<false>(v0.x) + W1 * fp8pk2<false>(v1.x)
           + W2 * fp8pk2<false>(v2.x) + W3 * fp8pk2<false>(v3.x);
    ac[1] += W0 * fp8pk2<true>(v0.x)  + W1 * fp8pk2<true>(v1.x)
           + W2 * fp8pk2<true>(v2.x)  + W3 * fp8pk2<true>(v3.x);
    ac[2] += W0 * fp8pk2<false>(v0.y) + W1 * fp8pk2<false>(v1.y)
           + W2 * fp8pk2<false>(v2.y) + W3 * fp8pk2<false>(v3.y);
    ac[3] += W0 * fp8pk2<true>(v0.y)  + W1 * fp8pk2<true>(v1.y)
           + W2 * fp8pk2<true>(v2.y)  + W3 * fp8pk2<true>(v3.y);
  }
  for (; e < end; e++){
    unsigned s = (unsigned)sorted_src[e];
    float wg = __expf(lrelu(as_arr[s] + a_d));
    den += wg;
    uint2 v = *(const uint2*)(h8 + (((size_t)s << 6) | coff));
    floatx2 wv = {wg, wg};
    ac[0] += wv * fp8pk2<false>(v.x);
    ac[1] += wv * fp8pk2<true>(v.x);
    ac[2] += wv * fp8pk2<false>(v.y);
    ac[3] += wv * fp8pk2<true>(v.y);
  }
  float inv = 0.015625f / (den + 1e-16f);    // 1/64 undoes fp8 pre-scale
  int cb = q * 8;
  float4 bA = *(const float4*)&bias[cb];
  float4 bB = *(const float4*)&bias[cb + 4];
  float bb[8] = {bA.x, bA.y, bA.z, bA.w, bB.x, bB.y, bB.z, bB.w};
  float p0 = 0.f, p1 = 0.f, p2 = 0.f, p3 = 0.f, p4 = 0.f;
  #pragma unroll
  for (int j = 0; j < 8; j++){
    float v = ((j & 1) ? ac[j >> 1].y : ac[j >> 1].x);
    float h = eluf(v * inv + bb[j]);
    const float* wr = &w_lds[(cb + j) * 5];
    p0 += h * wr[0];
    p1 += h * wr[1];
    p2 += h * wr[2];
    p3 += h * wr[3];
    p4 += h * wr[4];
  }
  p0 += __shfl_xor(p0, 1, 64); p0 += __shfl_xor(p0, 2, 64); p0 += __shfl_xor(p0, 4, 64);
  p1 += __shfl_xor(p1, 1, 64); p1 += __shfl_xor(p1, 2, 64); p1 += __shfl_xor(p1, 4, 64);
  p2 += __shfl_xor(p2, 1, 64); p2 += __shfl_xor(p2, 2, 64); p2 += __shfl_xor(p2, 4, 64);
  p3 += __shfl_xor(p3, 1, 64); p3 += __shfl_xor(p3, 2, 64); p3 += __shfl_xor(p3, 4, 64);
  p4 += __shfl_xor(p4, 1, 64); p4 += __shfl_xor(p4, 2, 64); p4 += __shfl_xor(p4, 4, 64);
  if (q == 0){
    float* o = out + (size_t)d * 5;
    o[0] = p0 + fb5[0];
    o[1] = p1 + fb5[1];
    o[2] = p2 + fb5[2];
    o[3] = p3 + fb5[3];
    o[4] = p4 + fb5[4];
  }
}

// ---------------- host launch ----------------

extern "C" void kernel_launch(void* const* d_in, const int* in_sizes, int n_in,
                              void* d_out, int out_size, void* d_ws, size_t ws_size,
                              hipStream_t stream){
  const int*   x    = (const int*)d_in[0];
  const int*   ei   = (const int*)d_in[1];
  const float* emb  = (const float*)d_in[2];
  const float* W1   = (const float*)d_in[3];
  const float* a1s  = (const float*)d_in[4];
  const float* a1d  = (const float*)d_in[5];
  const float* b1   = (const float*)d_in[6];
  const float* W2   = (const float*)d_in[7];
  const float* a2s  = (const float*)d_in[8];
  const float* a2d  = (const float*)d_in[9];
  const float* b2   = (const float*)d_in[10];
  const float* W3   = (const float*)d_in[11];
  const float* a3s  = (const float*)d_in[12];
  const float* a3d  = (const float*)d_in[13];
  const float* b3   = (const float*)d_in[14];
  const float* fcw  = (const float*)d_in[15];
  const float* fcb  = (const float*)d_in[16];
  float* out = (float*)d_out;

  const int N = in_sizes[0];
  const int E = in_sizes[1] / 2;
  const int dpb = N / NB;             // dst per bucket (512 for N=131072)
  int shift = 0;
  while ((1 << shift) < dpb) shift++; // log2(dpb)
  const int PB = (E + 4095) / 4096;   // partition blocks

  // workspace partition (256B aligned)
  char* base = (char*)d_ws;
  size_t off = 0;
  auto alloc = [&](size_t bytes) -> void* {
    void* p = base + off;
    off += (bytes + 255) & ~(size_t)255;
    return p;
  };
  unsigned short* bufB    = (unsigned short*)alloc((size_t)N * 256 * 2);  // h1 (conv1 out)
  unsigned char*  buf8    = (unsigned char*)alloc((size_t)N * 256);      // h2 fp8 x64
  unsigned char*  buf8b   = (unsigned char*)alloc((size_t)N * 64);       // h3 fp8 x64
  float* alpha_s          = (float*)alloc((size_t)N * 4 * 4);
  float* alpha_d          = (float*)alloc((size_t)N * 4 * 4);
  float* as3              = (float*)alloc((size_t)N * 4);
  float* ad3              = (float*)alloc((size_t)N * 4);
  int* row_ptr            = (int*)alloc((size_t)(N + 1) * 4);
  int* sorted_src         = (int*)alloc((size_t)(E + N) * 4);
  int* perm               = (int*)alloc((size_t)N * 4);
  uint2* cnt5             = (uint2*)alloc((size_t)N * 8);
  unsigned* bbuf          = (unsigned*)alloc((size_t)NB * CAP * 4);
  int* gcnt               = (int*)alloc((size_t)NB * 4);
  int* gbase              = (int*)alloc((size_t)(NB + 1) * 4);
  float* T1               = (float*)alloc(5 * 256 * 4);
  float* wt_tab           = (float*)alloc(100 * 4);
  unsigned short* Wp2     = (unsigned short*)alloc(256 * 256 * 2);
  unsigned short* Wp3     = (unsigned short*)alloc(64 * 256 * 2);

  // ---- CSR build (bucket partition) + weight prep, fused ----
  (void)hipMemsetAsync(gcnt, 0, (size_t)NB * 4, stream);
  part_prep_k<<<PB + 321, 256, 0, stream>>>(ei, E, shift, x, gcnt, bbuf, PB,
                                            W2, Wp2, W3, Wp3, emb, W1, a1s, a1d, T1, wt_tab);
  bscan_k<<<1, 256, 0, stream>>>(gcnt, gbase, row_ptr, N, dpb);
  sort_k<<<NB, 256, 0, stream>>>(bbuf, gcnt, gbase, x, row_ptr, sorted_src, perm, cnt5, dpb);

  // ---- conv1: histogram aggregation (counts precomputed) -> bufB [N,256] bf16 ----
  agg1_k<<<N / 256, 256, 0, stream>>>(x, T1, wt_tab, cnt5, b1, bufB);

  // ---- conv2: GEMM -> h2 fp8 (x64) + fused head alphas ----
  gemm_lds_k<128, 1, true><<<dim3(N / 128, 2), 256, 0, stream>>>(bufB, Wp2, buf8, 256,
                                                                 a2s, a2d, alpha_s, alpha_d);
  // ---- conv2 aggregation + FUSED conv3 GEMM (64 dsts/block) ----
  agg4g_k<<<N / 64, 256, 0, stream>>>(buf8, alpha_s, alpha_d, row_ptr, sorted_src, perm, b2,
                                      Wp3, a3s, a3d, buf8b, as3, ad3);

  // ---- conv3 aggregation + fused final FC -> d_out [N,5] f32 ----
  agg3_k<<<N / 32, 256, 0, stream>>>(buf8b, as3, ad3, row_ptr, sorted_src, perm, b3,
                                     fcw, fcb, out);
}